// Round 7
// baseline (134.663 us; speedup 1.0000x reference)
//
#include <hip/hip_runtime.h>
#include <hip/hip_bf16.h>

#define NSP   1024
#define ROWS  4
#define BLK   512   // gather block: 512 threads, each owns 2 species
#define MAXK  160   // max total terms per species column (Poisson λ≈78; max over 1024 ≈ 107)

// ---- workspace layout (bytes) ----
// counts  : int[2*NSP]            @ 0      ([0,NSP): 2nd-order count, [NSP,2NSP): 1st-order count)
// terms_T : int2[MAXK * NSP]      @ 8192   column-major: slot k of species s at [k*NSP+s]
//           2nd-order fills slots from 0 upward; 1st-order fills from MAXK-1 downward.
#define WS_COUNTS 0
#define WS_TERMS  8192

// Grid-wide scatter: build padded column-major term table using global atomics.
// 2nd-order term: (a | b<<16, (rate*den) bits), slots [0, c2).
// 1st-order term: (a, rate bits), slots [MAXK-c1, MAXK).
__global__ __launch_bounds__(256) void scatter_kernel(
    const int* __restrict__ r1, const int* __restrict__ o1,
    const float* __restrict__ rates1, int n1,
    const int* __restrict__ r2a, const int* __restrict__ r2b,
    const int* __restrict__ o2, const float* __restrict__ rates2, int n2,
    const float* __restrict__ den_ptr,
    int* __restrict__ counts, int2* __restrict__ terms_T)
{
    const float den = den_ptr[0];
    const int total = n1 + n2;
    int i = blockIdx.x * blockDim.x + threadIdx.x;
    int stride = gridDim.x * blockDim.x;

    for (int t = i; t < total; t += stride) {
        if (t < n1) {
            int s = o1[t];
            int pos = atomicAdd(&counts[NSP + s], 1);
            int slot = MAXK - 1 - pos;
            if (slot >= 0)
                terms_T[(size_t)slot * NSP + s] =
                    make_int2(r1[t], __float_as_int(rates1[t]));
        } else {
            int u = t - n1;
            int s = o2[u];
            int pos = atomicAdd(&counts[s], 1);
            if (pos < MAXK)
                terms_T[(size_t)pos * NSP + s] =
                    make_int2(r2a[u] | (r2b[u] << 16),
                              __float_as_int(rates2[u] * den));
        }
    }
}

__global__ __launch_bounds__(BLK) void gather_kernel(
    const float* __restrict__ y,
    const int* __restrict__ counts,
    const int2* __restrict__ terms_T,
    float* __restrict__ out)
{
    // Four batch rows interleaved as float4 -> one ds_read_b128 serves all 4 rows.
    __shared__ float4 ys[NSP];

    const int tid  = threadIdx.x;
    const int row0 = blockIdx.x * ROWS;

    // Stage 4 rows (4096 floats) with 512 threads.
    for (int i = tid; i < ROWS * NSP; i += BLK) {
        int r = i >> 10;
        int c = i & (NSP - 1);
        ((float*)&ys[c])[r] = y[(size_t)(row0 + r) * NSP + c];
    }
    __syncthreads();

    // Each thread owns 2 species: tid and tid+512 (halves per-wave count imbalance).
#pragma unroll
    for (int j = 0; j < 2; ++j) {
        const int s  = tid + j * BLK;
        const int c2 = counts[s];        // 2nd-order terms, slots [0, c2)
        const int c1 = counts[NSP + s];  // 1st-order terms, slots [MAXK-c1, MAXK)

        float4 acc = make_float4(0.0f, 0.0f, 0.0f, 0.0f);

        // 2nd-order: acc[r] += w * y[r][a] * y[r][b]
#pragma unroll 2
        for (int k = 0; k < c2; ++k) {
            const int2 e = terms_T[(size_t)k * NSP + s];
            const int a = e.x & 0xFFFF;
            const int b = e.x >> 16;
            const float w = __int_as_float(e.y);
            const float4 ya = ys[a];
            const float4 yb = ys[b];
            acc.x += w * ya.x * yb.x;
            acc.y += w * ya.y * yb.y;
            acc.z += w * ya.z * yb.z;
            acc.w += w * ya.w * yb.w;
        }

        // 1st-order: acc[r] += w * y[r][a]
#pragma unroll 2
        for (int q = 0; q < c1; ++q) {
            const int2 e = terms_T[(size_t)(MAXK - 1 - q) * NSP + s];
            const float w = __int_as_float(e.y);
            const float4 ya = ys[e.x];
            acc.x += w * ya.x;
            acc.y += w * ya.y;
            acc.z += w * ya.z;
            acc.w += w * ya.w;
        }

        out[(size_t)(row0 + 0) * NSP + s] = acc.x;
        out[(size_t)(row0 + 1) * NSP + s] = acc.y;
        out[(size_t)(row0 + 2) * NSP + s] = acc.z;
        out[(size_t)(row0 + 3) * NSP + s] = acc.w;
    }
}

extern "C" void kernel_launch(void* const* d_in, const int* in_sizes, int n_in,
                              void* d_out, int out_size, void* d_ws, size_t ws_size,
                              hipStream_t stream) {
    const float* y      = (const float*)d_in[1];
    const float* rates1 = (const float*)d_in[2];
    const float* rates2 = (const float*)d_in[3];
    const float* den    = (const float*)d_in[4];
    const int* r1  = (const int*)d_in[5];
    const int* r2a = (const int*)d_in[6];
    const int* r2b = (const int*)d_in[7];
    const int* o1  = (const int*)d_in[8];
    const int* o2  = (const int*)d_in[9];
    float* out = (float*)d_out;

    const int n_t1  = in_sizes[2];
    const int n_t2  = in_sizes[3];
    const int batch = in_sizes[1] / NSP;

    char* ws = (char*)d_ws;
    int*  counts  = (int*)(ws + WS_COUNTS);
    int2* terms_T = (int2*)(ws + WS_TERMS);

    hipMemsetAsync(counts, 0, 2 * NSP * sizeof(int), stream);
    scatter_kernel<<<256, 256, 0, stream>>>(r1, o1, rates1, n_t1,
                                            r2a, r2b, o2, rates2, n_t2,
                                            den, counts, terms_T);
    gather_kernel<<<batch / ROWS, BLK, 0, stream>>>(y, counts, terms_T, out);
}

// Round 8
// 114.264 us; speedup vs baseline: 1.1785x; 1.1785x over previous
//
#include <hip/hip_runtime.h>
#include <hip/hip_bf16.h>

#define NSP    1024
#define ROWS   4
#define BLK    256   // gather block: 256 threads, each owns 1 species of a quarter
#define QUARTS 4     // species quarters per row-group
#define MAXK   160   // max total terms per species column (Poisson λ≈78; max over 1024 ≈ 110)

// ---- workspace layout (bytes) ----
// counts  : int[2*NSP]            @ 0      ([0,NSP): 2nd-order count, [NSP,2NSP): 1st-order count)
// terms_T : int2[MAXK * NSP]      @ 8192   column-major: slot k of species s at [k*NSP+s]
//           2nd-order fills slots from 0 upward; 1st-order fills from MAXK-1 downward.
#define WS_COUNTS 0
#define WS_TERMS  8192

__global__ __launch_bounds__(256) void scatter_kernel(
    const int* __restrict__ r1, const int* __restrict__ o1,
    const float* __restrict__ rates1, int n1,
    const int* __restrict__ r2a, const int* __restrict__ r2b,
    const int* __restrict__ o2, const float* __restrict__ rates2, int n2,
    const float* __restrict__ den_ptr,
    int* __restrict__ counts, int2* __restrict__ terms_T)
{
    const float den = den_ptr[0];
    const int total = n1 + n2;
    int i = blockIdx.x * blockDim.x + threadIdx.x;
    int stride = gridDim.x * blockDim.x;

    for (int t = i; t < total; t += stride) {
        if (t < n1) {
            int s = o1[t];
            int pos = atomicAdd(&counts[NSP + s], 1);
            int slot = MAXK - 1 - pos;
            if (slot >= 0)
                terms_T[(size_t)slot * NSP + s] =
                    make_int2(r1[t], __float_as_int(rates1[t]));
        } else {
            int u = t - n1;
            int s = o2[u];
            int pos = atomicAdd(&counts[s], 1);
            if (pos < MAXK)
                terms_T[(size_t)pos * NSP + s] =
                    make_int2(r2a[u] | (r2b[u] << 16),
                              __float_as_int(rates2[u] * den));
        }
    }
}

// grid = (batch/ROWS) * QUARTS blocks of 256 threads.
// blockIdx.x / QUARTS = row-group; blockIdx.x % QUARTS = species quarter.
// 4 blocks/CU co-resident (64 KB LDS) -> 16 waves/CU for latency hiding.
__global__ __launch_bounds__(BLK) void gather_kernel(
    const float* __restrict__ y,
    const int* __restrict__ counts,
    const int2* __restrict__ terms_T,
    float* __restrict__ out)
{
    // Four batch rows interleaved as float4 -> one ds_read_b128 serves all 4 rows.
    __shared__ float4 ys[NSP];

    const int tid   = threadIdx.x;
    const int rg    = blockIdx.x / QUARTS;
    const int quart = blockIdx.x % QUARTS;
    const int row0  = rg * ROWS;

    // Stage all 4 rows (4096 floats) with 256 threads (coalesced reads).
    for (int i = tid; i < ROWS * NSP; i += BLK) {
        int r = i >> 10;
        int c = i & (NSP - 1);
        ((float*)&ys[c])[r] = y[(size_t)(row0 + r) * NSP + c];
    }
    __syncthreads();

    const int s  = quart * BLK + tid;   // this thread's species
    const int c2 = counts[s];           // 2nd-order terms, slots [0, c2)
    const int c1 = counts[NSP + s];     // 1st-order terms, slots [MAXK-c1, MAXK)

    float4 acc = make_float4(0.0f, 0.0f, 0.0f, 0.0f);

    // 2nd-order: acc[r] += w * y[r][a] * y[r][b]
#pragma unroll 4
    for (int k = 0; k < c2; ++k) {
        const int2 e = terms_T[(size_t)k * NSP + s];
        const int a = e.x & 0xFFFF;
        const int b = e.x >> 16;
        const float w = __int_as_float(e.y);
        const float4 ya = ys[a];
        const float4 yb = ys[b];
        acc.x += w * ya.x * yb.x;
        acc.y += w * ya.y * yb.y;
        acc.z += w * ya.z * yb.z;
        acc.w += w * ya.w * yb.w;
    }

    // 1st-order: acc[r] += w * y[r][a]
#pragma unroll 4
    for (int q = 0; q < c1; ++q) {
        const int2 e = terms_T[(size_t)(MAXK - 1 - q) * NSP + s];
        const float w = __int_as_float(e.y);
        const float4 ya = ys[e.x];
        acc.x += w * ya.x;
        acc.y += w * ya.y;
        acc.z += w * ya.z;
        acc.w += w * ya.w;
    }

    out[(size_t)(row0 + 0) * NSP + s] = acc.x;
    out[(size_t)(row0 + 1) * NSP + s] = acc.y;
    out[(size_t)(row0 + 2) * NSP + s] = acc.z;
    out[(size_t)(row0 + 3) * NSP + s] = acc.w;
}

extern "C" void kernel_launch(void* const* d_in, const int* in_sizes, int n_in,
                              void* d_out, int out_size, void* d_ws, size_t ws_size,
                              hipStream_t stream) {
    const float* y      = (const float*)d_in[1];
    const float* rates1 = (const float*)d_in[2];
    const float* rates2 = (const float*)d_in[3];
    const float* den    = (const float*)d_in[4];
    const int* r1  = (const int*)d_in[5];
    const int* r2a = (const int*)d_in[6];
    const int* r2b = (const int*)d_in[7];
    const int* o1  = (const int*)d_in[8];
    const int* o2  = (const int*)d_in[9];
    float* out = (float*)d_out;

    const int n_t1  = in_sizes[2];
    const int n_t2  = in_sizes[3];
    const int batch = in_sizes[1] / NSP;

    char* ws = (char*)d_ws;
    int*  counts  = (int*)(ws + WS_COUNTS);
    int2* terms_T = (int2*)(ws + WS_TERMS);

    hipMemsetAsync(counts, 0, 2 * NSP * sizeof(int), stream);
    scatter_kernel<<<256, 256, 0, stream>>>(r1, o1, rates1, n_t1,
                                            r2a, r2b, o2, rates2, n_t2,
                                            den, counts, terms_T);
    gather_kernel<<<(batch / ROWS) * QUARTS, BLK, 0, stream>>>(y, counts, terms_T, out);
}